// Round 1
// baseline (1612.281 us; speedup 1.0000x reference)
//
#include <hip/hip_runtime.h>

// Problem constants (fixed by the reference)
#define N_ROWS 262144
#define D 80           // input feature dim
#define DA 81          // augmented dim [x, 1]
#define MSTRIDE 84     // column stride for bilinear matrices (16B-aligned cols)
#define DOUT 160
#define EPS 1e-5f

// ws layout (in floats)
#define S_OFF   0                      // 3 x (81*81) second-moment matrices
#define S_SIZE  (DA * DA)              // 6561
#define T_OFF   (3 * S_SIZE)           // 19683 : T = W~ @ S~  (3 x 160x81)
#define T_SIZE  (DOUT * DA)            // 12960
#define WP_OFF  (T_OFF + 3 * T_SIZE)   // 58563 : W' effective weights (3 x 160x81)
#define WP_SIZE (DOUT * DA)
#define MC_OFF  (WP_OFF + 3 * WP_SIZE) // 97443 : Mc[q][k*84+i] = M_q[i,k] (3 x 81x84)
#define MC_SIZE (DA * MSTRIDE)         // 6804

// ---------------------------------------------------------------------------
// K1: per-input augmented second moments S~ = sum_rows [x,1][x,1]^T
//     (80x80 block via register-tiled outer products, col-sums for row/col 80)
// ---------------------------------------------------------------------------
__global__ void k1_moments(const float* __restrict__ xs,
                           const float* __restrict__ xl,
                           const float* __restrict__ xr,
                           float* __restrict__ ws) {
    const float* x = (blockIdx.y == 0) ? xs : (blockIdx.y == 1) ? xl : xr;
    float* S = ws + S_OFF + blockIdx.y * S_SIZE;

    __shared__ float tile[32][DA];  // 32 rows x 81 (pad: 81 odd -> conflict-light)

    const int tid = threadIdx.x;
    const int tx = tid & 15;        // i-tile
    const int ty = tid >> 4;        // j-tile
    const int i0 = tx * 5, j0 = ty * 5;

    float acc[5][5];
#pragma unroll
    for (int a = 0; a < 5; a++)
#pragma unroll
        for (int b = 0; b < 5; b++) acc[a][b] = 0.f;
    float csum = 0.f;

    const int rowsPerBlock = N_ROWS / 256;  // gridDim.x == 256 -> 1024
    const int row0 = blockIdx.x * rowsPerBlock;

    for (int t0 = 0; t0 < rowsPerBlock; t0 += 32) {
        __syncthreads();
        // stage 32 rows, coalesced float4
        for (int idx = tid; idx < 32 * 20; idx += 256) {
            int r = idx / 20, c = idx % 20;
            float4 v = reinterpret_cast<const float4*>(
                x + (size_t)(row0 + t0 + r) * D)[c];
            tile[r][c * 4 + 0] = v.x;
            tile[r][c * 4 + 1] = v.y;
            tile[r][c * 4 + 2] = v.z;
            tile[r][c * 4 + 3] = v.w;
        }
        __syncthreads();

#pragma unroll 4
        for (int r = 0; r < 32; r++) {
            float xi[5], xj[5];
#pragma unroll
            for (int u = 0; u < 5; u++) {
                xi[u] = tile[r][i0 + u];
                xj[u] = tile[r][j0 + u];
            }
#pragma unroll
            for (int a = 0; a < 5; a++)
#pragma unroll
                for (int b = 0; b < 5; b++) acc[a][b] += xi[a] * xj[b];
        }
        if (tid < D) {
#pragma unroll 4
            for (int r = 0; r < 32; r++) csum += tile[r][tid];
        }
    }

#pragma unroll
    for (int a = 0; a < 5; a++)
#pragma unroll
        for (int b = 0; b < 5; b++)
            atomicAdd(&S[(i0 + a) * DA + (j0 + b)], acc[a][b]);
    if (tid < D) {
        atomicAdd(&S[tid * DA + D], csum);  // column 80
        atomicAdd(&S[D * DA + tid], csum);  // row 80
    }
    // corner S[80,80] = N handled inline in k2_T
}

// ---------------------------------------------------------------------------
// K2a: T[p][j][i] = sum_k W~[j,k] * S~[k,i]   (W~ = [W | b])
// ---------------------------------------------------------------------------
__global__ void k2_T(const float* __restrict__ Ws, const float* __restrict__ bs,
                     const float* __restrict__ Wl, const float* __restrict__ bl,
                     const float* __restrict__ Wr, const float* __restrict__ br,
                     float* __restrict__ ws) {
    int e = blockIdx.x * 256 + threadIdx.x;
    if (e >= 3 * DOUT * DA) return;
    int p = e / (DOUT * DA);
    int rem = e - p * (DOUT * DA);
    int j = rem / DA, i = rem - j * DA;

    const float* W = (p == 0) ? Ws : (p == 1) ? Wl : Wr;
    const float* b = (p == 0) ? bs : (p == 1) ? bl : br;
    const float* S = ws + S_OFF + p * S_SIZE;

    float a0 = 0.f, a1 = 0.f;
    for (int k = 0; k < D; k += 2) {
        a0 += W[j * D + k] * S[k * DA + i];
        a1 += W[j * D + k + 1] * S[(k + 1) * DA + i];
    }
    float s80 = (i == D) ? (float)N_ROWS : S[D * DA + i];
    float acc = a0 + a1 + b[j] * s80;
    ws[T_OFF + p * T_SIZE + j * DA + i] = acc;
}

// ---------------------------------------------------------------------------
// K2b: per feature j: mu, var, a -> effective W'[j,:] (augmented)
// ---------------------------------------------------------------------------
__global__ void k2_scale(const float* __restrict__ Ws, const float* __restrict__ bs,
                         const float* __restrict__ gs, const float* __restrict__ bes,
                         const float* __restrict__ Wl, const float* __restrict__ bl,
                         const float* __restrict__ gl, const float* __restrict__ bel,
                         const float* __restrict__ Wr, const float* __restrict__ br,
                         const float* __restrict__ gr, const float* __restrict__ ber,
                         float* __restrict__ ws) {
    int e = blockIdx.x * 256 + threadIdx.x;
    if (e >= 3 * DOUT) return;
    int p = e / DOUT, j = e - p * DOUT;

    const float* W  = (p == 0) ? Ws  : (p == 1) ? Wl  : Wr;
    const float* b  = (p == 0) ? bs  : (p == 1) ? bl  : br;
    const float* g  = (p == 0) ? gs  : (p == 1) ? gl  : gr;
    const float* be = (p == 0) ? bes : (p == 1) ? bel : ber;

    const float* T = ws + T_OFF + p * T_SIZE + j * DA;
    float eh2 = 0.f;
    for (int k = 0; k < D; k++) eh2 += T[k] * W[j * D + k];
    eh2 += T[D] * b[j];
    const float invN = 1.0f / (float)N_ROWS;
    eh2 *= invN;
    float mu = T[D] * invN;
    float var = eh2 - mu * mu;
    float a = g[j] * rsqrtf(var + EPS);

    float* Wp = ws + WP_OFF + p * WP_SIZE + j * DA;
    for (int k = 0; k < D; k++) Wp[k] = a * W[j * D + k];
    Wp[D] = a * b[j] + be[j] - a * mu;
}

// ---------------------------------------------------------------------------
// K2c: bilinear matrices Mc[q][k*84+i] = sum_j W'_a[j,i] * W'_b[j,k]
//      q=0:(sub,left) q=1:(sub,right) q=2:(left,right)  (a = i-side)
// ---------------------------------------------------------------------------
__global__ void k2_M(float* __restrict__ ws) {
    int e = blockIdx.x * 256 + threadIdx.x;
    if (e >= 3 * DA * DA) return;
    int q = e / (DA * DA);
    int rem = e - q * (DA * DA);
    int k = rem / DA, i = rem - k * DA;

    int pa = (q == 2) ? 1 : 0;  // i-side: sub, sub, left
    int pb = (q == 0) ? 1 : 2;  // k-side: left, right, right
    const float* Wa = ws + WP_OFF + pa * WP_SIZE;
    const float* Wb = ws + WP_OFF + pb * WP_SIZE;

    float a0 = 0.f, a1 = 0.f;
    for (int j = 0; j < DOUT; j += 2) {
        a0 += Wa[j * DA + i] * Wb[j * DA + k];
        a1 += Wa[(j + 1) * DA + i] * Wb[(j + 1) * DA + k];
    }
    ws[MC_OFF + q * MC_SIZE + k * MSTRIDE + i] = a0 + a1;
}

// ---------------------------------------------------------------------------
// K3: per row: 3 bilinear sims -> softmax -> combine
// ---------------------------------------------------------------------------
__device__ __forceinline__ float bilin(const float* __restrict__ Mc,
                                       const float (&v)[D],
                                       const float* __restrict__ xk) {
    float acc = 0.f;
    for (int k = 0; k < D; k++) {
        const float* col = Mc + k * MSTRIDE;  // wave-uniform address -> s_load
        float d0 = 0.f, d1 = 0.f, d2 = 0.f, d3 = 0.f;
#pragma unroll
        for (int i = 0; i < D; i += 4) {
            d0 += col[i + 0] * v[i + 0];
            d1 += col[i + 1] * v[i + 1];
            d2 += col[i + 2] * v[i + 2];
            d3 += col[i + 3] * v[i + 3];
        }
        float d = ((d0 + d1) + (d2 + d3)) + col[D];  // v~[80] = 1
        acc += d * xk[k];
    }
    {   // k = 80 term (x~_k = 1)
        const float* col = Mc + D * MSTRIDE;
        float d0 = 0.f, d1 = 0.f, d2 = 0.f, d3 = 0.f;
#pragma unroll
        for (int i = 0; i < D; i += 4) {
            d0 += col[i + 0] * v[i + 0];
            d1 += col[i + 1] * v[i + 1];
            d2 += col[i + 2] * v[i + 2];
            d3 += col[i + 3] * v[i + 3];
        }
        acc += ((d0 + d1) + (d2 + d3)) + col[D];
    }
    return acc;
}

__global__ void k3_main(const float* __restrict__ xs_g,
                        const float* __restrict__ xl_g,
                        const float* __restrict__ xr_g,
                        const float* __restrict__ ws,
                        float* __restrict__ out) {
    const int row = blockIdx.x * 256 + threadIdx.x;
    const float* xs = xs_g + (size_t)row * D;
    const float* xl = xl_g + (size_t)row * D;
    const float* xr = xr_g + (size_t)row * D;
    const float* Msl = ws + MC_OFF + 0 * MC_SIZE;
    const float* Msr = ws + MC_OFF + 1 * MC_SIZE;
    const float* Mlr = ws + MC_OFF + 2 * MC_SIZE;

    float v[D];
#pragma unroll
    for (int i = 0; i < D; i += 4) {
        float4 t = *reinterpret_cast<const float4*>(xs + i);
        v[i] = t.x; v[i + 1] = t.y; v[i + 2] = t.z; v[i + 3] = t.w;
    }
    float s0 = bilin(Msl, v, xl);   // sub-left
    float s1 = bilin(Msr, v, xr);   // sub-right

#pragma unroll
    for (int i = 0; i < D; i += 4) {
        float4 t = *reinterpret_cast<const float4*>(xl + i);  // L2-hot reload
        v[i] = t.x; v[i + 1] = t.y; v[i + 2] = t.z; v[i + 3] = t.w;
    }
    float s2 = bilin(Mlr, v, xr);   // left-right

    float m = fmaxf(s0, fmaxf(s1, s2));
    float e0 = __expf(s0 - m), e1 = __expf(s1 - m), e2 = __expf(s2 - m);
    float inv = 1.0f / (e0 + e1 + e2);
    float p0 = e0 * inv, p1 = e1 * inv, p2 = e2 * inv;

    float* o = out + (size_t)row * D;
#pragma unroll
    for (int i = 0; i < D; i += 4) {
        float4 r4 = *reinterpret_cast<const float4*>(xr + i);
        float4 s4 = *reinterpret_cast<const float4*>(xs + i);
        float4 ov;
        ov.x = p0 * v[i + 0] + p1 * r4.x + p2 * s4.x;  // v holds left
        ov.y = p0 * v[i + 1] + p1 * r4.y + p2 * s4.y;
        ov.z = p0 * v[i + 2] + p1 * r4.z + p2 * s4.z;
        ov.w = p0 * v[i + 3] + p1 * r4.w + p2 * s4.w;
        *reinterpret_cast<float4*>(o + i) = ov;
    }
}

// ---------------------------------------------------------------------------
extern "C" void kernel_launch(void* const* d_in, const int* in_sizes, int n_in,
                              void* d_out, int out_size, void* d_ws, size_t ws_size,
                              hipStream_t stream) {
    const float* xs = (const float*)d_in[0];
    const float* xl = (const float*)d_in[1];
    const float* xr = (const float*)d_in[2];
    const float* Wsub = (const float*)d_in[3];
    const float* bsub = (const float*)d_in[4];
    const float* gsub = (const float*)d_in[5];
    const float* besub = (const float*)d_in[6];
    const float* Wleft = (const float*)d_in[7];
    const float* bleft = (const float*)d_in[8];
    const float* gleft = (const float*)d_in[9];
    const float* beleft = (const float*)d_in[10];
    const float* Wright = (const float*)d_in[11];
    const float* bright = (const float*)d_in[12];
    const float* gright = (const float*)d_in[13];
    const float* beright = (const float*)d_in[14];
    float* ws = (float*)d_ws;
    float* out = (float*)d_out;

    // zero the moment accumulators (ws is poisoned each call)
    hipMemsetAsync(ws + S_OFF, 0, 3 * S_SIZE * sizeof(float), stream);

    k1_moments<<<dim3(256, 3), 256, 0, stream>>>(xs, xl, xr, ws);
    k2_T<<<(3 * DOUT * DA + 255) / 256, 256, 0, stream>>>(
        Wsub, bsub, Wleft, bleft, Wright, bright, ws);
    k2_scale<<<(3 * DOUT + 255) / 256, 256, 0, stream>>>(
        Wsub, bsub, gsub, besub, Wleft, bleft, gleft, beleft,
        Wright, bright, gright, beright, ws);
    k2_M<<<(3 * DA * DA + 255) / 256, 256, 0, stream>>>(ws);
    k3_main<<<N_ROWS / 256, 256, 0, stream>>>(xs, xl, xr, ws, out);
}

// Round 2
// 1294.026 us; speedup vs baseline: 1.2459x; 1.2459x over previous
//
#include <hip/hip_runtime.h>

// Problem constants (fixed by the reference)
#define N_ROWS 262144
#define D 80           // input feature dim
#define DA 81          // augmented dim [x, 1]
#define MSTRIDE 84     // column stride for bilinear matrices
#define DOUT 160
#define EPS 1e-5f

// ws layout (in floats)
#define S_OFF   0                      // 3 x (81*81) second-moment matrices
#define S_SIZE  (DA * DA)              // 6561
#define T_OFF   (3 * S_SIZE)           // T = W~ @ S~  (3 x 160x81)
#define T_SIZE  (DOUT * DA)
#define WP_OFF  (T_OFF + 3 * T_SIZE)   // W' effective weights (3 x 160x81)
#define WP_SIZE (DOUT * DA)
#define MC_OFF  (WP_OFF + 3 * WP_SIZE) // Mc[q][k*84+i] = M_q[i,k] (3 x 81x84)
#define MC_SIZE (DA * MSTRIDE)

// ---------------------------------------------------------------------------
// K1: per-input augmented second moments S~ = sum_rows [x,1][x,1]^T
//     8x8 per-lane tiles over the UPPER TRIANGLE (55 pairs per wave),
//     float4 LDS reads, block-level LDS reduction, mirrored atomics.
// ---------------------------------------------------------------------------
__global__ __launch_bounds__(256) void k1_moments(const float* __restrict__ xs,
                                                  const float* __restrict__ xl,
                                                  const float* __restrict__ xr,
                                                  float* __restrict__ ws) {
    const float* x = (blockIdx.y == 0) ? xs : (blockIdx.y == 1) ? xl : xr;
    float* S = ws + S_OFF + blockIdx.y * S_SIZE;

    __shared__ float lds[3600];  // tile: 32x80 = 2560 floats; reduce: 3520+80

    const int tid = threadIdx.x;
    const int wave = tid >> 6;
    const int lane = tid & 63;

    // lane -> upper-triangle pair (ti<=tj) of the 10x10 8-chunk grid
    int ti = -1, tj = -1;
    if (lane < 55) {
        int l = lane, a = 0;
        while (l >= 10 - a) { l -= 10 - a; a++; }
        ti = a; tj = a + l;
    }

    float acc[8][8];
#pragma unroll
    for (int u = 0; u < 8; u++)
#pragma unroll
        for (int v = 0; v < 8; v++) acc[u][v] = 0.f;
    float csum[8];
#pragma unroll
    for (int u = 0; u < 8; u++) csum[u] = 0.f;

    const int rowsPerBlock = N_ROWS / 256;  // gridDim.x == 256 -> 1024
    const size_t base = (size_t)blockIdx.x * rowsPerBlock * D;

    for (int t0 = 0; t0 < rowsPerBlock; t0 += 32) {
        __syncthreads();
        // stage 32 rows (2560 floats = 640 float4), fully coalesced
        const float4* src = reinterpret_cast<const float4*>(x + base + (size_t)t0 * D);
        float4* dst4 = reinterpret_cast<float4*>(lds);
        for (int idx = tid; idx < 640; idx += 256) dst4[idx] = src[idx];
        __syncthreads();

        if (ti >= 0) {
            const int rbase = wave * 8;  // each wave owns 8 of the 32 rows
#pragma unroll 2
            for (int rr = 0; rr < 8; rr++) {
                const float* row = &lds[(rbase + rr) * D];
                float a8[8], b8[8];
                *reinterpret_cast<float4*>(&a8[0]) = *reinterpret_cast<const float4*>(&row[ti * 8]);
                *reinterpret_cast<float4*>(&a8[4]) = *reinterpret_cast<const float4*>(&row[ti * 8 + 4]);
                *reinterpret_cast<float4*>(&b8[0]) = *reinterpret_cast<const float4*>(&row[tj * 8]);
                *reinterpret_cast<float4*>(&b8[4]) = *reinterpret_cast<const float4*>(&row[tj * 8 + 4]);
#pragma unroll
                for (int u = 0; u < 8; u++)
#pragma unroll
                    for (int v = 0; v < 8; v++) acc[u][v] += a8[u] * b8[v];
                if (ti == tj) {
#pragma unroll
                    for (int u = 0; u < 8; u++) csum[u] += a8[u];
                }
            }
        }
    }

    // block-level reduce across the 4 waves (serialized rounds, LDS RMW)
    __syncthreads();
    for (int i = tid; i < 3600; i += 256) lds[i] = 0.f;
    __syncthreads();
    for (int w = 0; w < 4; w++) {
        if (wave == w && ti >= 0) {
            float* dst = &lds[lane * 64];
#pragma unroll
            for (int u = 0; u < 8; u++)
#pragma unroll
                for (int v = 0; v < 8; v++) dst[u * 8 + v] += acc[u][v];
            if (ti == tj) {
#pragma unroll
                for (int u = 0; u < 8; u++) lds[3520 + ti * 8 + u] += csum[u];
            }
        }
        __syncthreads();
    }

    // global atomics (upper triangle + mirror)
    for (int e = tid; e < 3520; e += 256) {
        int p = e >> 6, o = e & 63;
        int l = p, a = 0;
        while (l >= 10 - a) { l -= 10 - a; a++; }
        const int pi = a, pj = a + l;
        const int i = pi * 8 + (o >> 3), j = pj * 8 + (o & 7);
        const float v = lds[e];
        atomicAdd(&S[i * DA + j], v);
        if (pi != pj) atomicAdd(&S[j * DA + i], v);
    }
    for (int c = tid; c < D; c += 256) {
        const float v = lds[3520 + c];
        atomicAdd(&S[c * DA + D], v);  // column 80
        atomicAdd(&S[D * DA + c], v);  // row 80
    }
    // corner S[80,80] = N handled inline in k2_T
}

// ---------------------------------------------------------------------------
// K2a: T[p][j][i] = sum_k W~[j,k] * S~[k,i]   (W~ = [W | b])
// ---------------------------------------------------------------------------
__global__ void k2_T(const float* __restrict__ Ws, const float* __restrict__ bs,
                     const float* __restrict__ Wl, const float* __restrict__ bl,
                     const float* __restrict__ Wr, const float* __restrict__ br,
                     float* __restrict__ ws) {
    int e = blockIdx.x * 256 + threadIdx.x;
    if (e >= 3 * DOUT * DA) return;
    int p = e / (DOUT * DA);
    int rem = e - p * (DOUT * DA);
    int j = rem / DA, i = rem - j * DA;

    const float* W = (p == 0) ? Ws : (p == 1) ? Wl : Wr;
    const float* b = (p == 0) ? bs : (p == 1) ? bl : br;
    const float* S = ws + S_OFF + p * S_SIZE;

    float a0 = 0.f, a1 = 0.f;
    for (int k = 0; k < D; k += 2) {
        a0 += W[j * D + k] * S[k * DA + i];
        a1 += W[j * D + k + 1] * S[(k + 1) * DA + i];
    }
    float s80 = (i == D) ? (float)N_ROWS : S[D * DA + i];
    ws[T_OFF + p * T_SIZE + j * DA + i] = a0 + a1 + b[j] * s80;
}

// ---------------------------------------------------------------------------
// K2b: per feature j: mu, var, a -> effective W'[j,:] (augmented)
// ---------------------------------------------------------------------------
__global__ void k2_scale(const float* __restrict__ Ws, const float* __restrict__ bs,
                         const float* __restrict__ gs, const float* __restrict__ bes,
                         const float* __restrict__ Wl, const float* __restrict__ bl,
                         const float* __restrict__ gl, const float* __restrict__ bel,
                         const float* __restrict__ Wr, const float* __restrict__ br,
                         const float* __restrict__ gr, const float* __restrict__ ber,
                         float* __restrict__ ws) {
    int e = blockIdx.x * 256 + threadIdx.x;
    if (e >= 3 * DOUT) return;
    int p = e / DOUT, j = e - p * DOUT;

    const float* W  = (p == 0) ? Ws  : (p == 1) ? Wl  : Wr;
    const float* b  = (p == 0) ? bs  : (p == 1) ? bl  : br;
    const float* g  = (p == 0) ? gs  : (p == 1) ? gl  : gr;
    const float* be = (p == 0) ? bes : (p == 1) ? bel : ber;

    const float* T = ws + T_OFF + p * T_SIZE + j * DA;
    float eh2 = 0.f;
    for (int k = 0; k < D; k++) eh2 += T[k] * W[j * D + k];
    eh2 += T[D] * b[j];
    const float invN = 1.0f / (float)N_ROWS;
    eh2 *= invN;
    float mu = T[D] * invN;
    float var = eh2 - mu * mu;
    float a = g[j] * rsqrtf(var + EPS);

    float* Wp = ws + WP_OFF + p * WP_SIZE + j * DA;
    for (int k = 0; k < D; k++) Wp[k] = a * W[j * D + k];
    Wp[D] = a * b[j] + be[j] - a * mu;
}

// ---------------------------------------------------------------------------
// K2c: bilinear matrices Mc[q][k*84+i] = sum_j W'_a[j,i] * W'_b[j,k]
//      q=0:(sub,left) q=1:(sub,right) q=2:(left,right)  (a = i-side/regs,
//      b = k-side/LDS in k3)
// ---------------------------------------------------------------------------
__global__ void k2_M(float* __restrict__ ws) {
    int e = blockIdx.x * 256 + threadIdx.x;
    if (e >= 3 * DA * DA) return;
    int q = e / (DA * DA);
    int rem = e - q * (DA * DA);
    int k = rem / DA, i = rem - k * DA;

    int pa = (q == 2) ? 1 : 0;  // i-side: sub, sub, left
    int pb = (q == 0) ? 1 : 2;  // k-side: left, right, right
    const float* Wa = ws + WP_OFF + pa * WP_SIZE;
    const float* Wb = ws + WP_OFF + pb * WP_SIZE;

    float a0 = 0.f, a1 = 0.f;
    for (int j = 0; j < DOUT; j += 2) {
        a0 += Wa[j * DA + i] * Wb[j * DA + k];
        a1 += Wa[(j + 1) * DA + i] * Wb[(j + 1) * DA + k];
    }
    ws[MC_OFF + q * MC_SIZE + k * MSTRIDE + i] = a0 + a1;
}

// ---------------------------------------------------------------------------
// K3: per row: 3 bilinear sims -> softmax -> combine.
//     i-side vector in regs (compile-time indexed, fully unrolled inner),
//     k-side = thread's OWN row in LDS (runtime-indexable private buffer).
//     All global traffic flows through LDS fully coalesced.
// ---------------------------------------------------------------------------
#define K3_ROWS 128
#define K3_F4   (K3_ROWS * D / 4)   // 2560 float4 per block chunk

__device__ __forceinline__ float bilin(const float* __restrict__ Mc,
                                       const float (&v)[D],
                                       const float* __restrict__ wlds) {
    float acc = 0.f;
#pragma unroll 4
    for (int k = 0; k < D; k++) {
        const float* col = Mc + k * MSTRIDE;  // wave-uniform -> s_load
        float d0 = 0.f, d1 = 0.f, d2 = 0.f, d3 = 0.f;
#pragma unroll
        for (int i = 0; i < D; i += 4) {
            d0 += col[i + 0] * v[i + 0];
            d1 += col[i + 1] * v[i + 1];
            d2 += col[i + 2] * v[i + 2];
            d3 += col[i + 3] * v[i + 3];
        }
        float d = ((d0 + d1) + (d2 + d3)) + col[D];  // aug element of v = 1
        acc += d * wlds[k];                          // own-row LDS read
    }
    {   // k = 80 term (aug element of w = 1)
        const float* col = Mc + D * MSTRIDE;
        float d0 = 0.f, d1 = 0.f, d2 = 0.f, d3 = 0.f;
#pragma unroll
        for (int i = 0; i < D; i += 4) {
            d0 += col[i + 0] * v[i + 0];
            d1 += col[i + 1] * v[i + 1];
            d2 += col[i + 2] * v[i + 2];
            d3 += col[i + 3] * v[i + 3];
        }
        acc += ((d0 + d1) + (d2 + d3)) + col[D];
    }
    return acc;
}

__global__ __launch_bounds__(K3_ROWS) void k3_main(const float* __restrict__ xs_g,
                                                   const float* __restrict__ xl_g,
                                                   const float* __restrict__ xr_g,
                                                   const float* __restrict__ ws,
                                                   float* __restrict__ out) {
    __shared__ float lds[K3_ROWS * D];  // 40 KB
    const int tid = threadIdx.x;
    const size_t blockBase = (size_t)blockIdx.x * K3_ROWS * D;
    float4* lds4 = reinterpret_cast<float4*>(lds);
    float* myrow = &lds[tid * D];
    const float4* myrow4 = reinterpret_cast<const float4*>(myrow);

    const float* Msl = ws + MC_OFF + 0 * MC_SIZE;
    const float* Msr = ws + MC_OFF + 1 * MC_SIZE;
    const float* Mlr = ws + MC_OFF + 2 * MC_SIZE;

    float v0[D], v1[D];  // xs, xl in registers

    // ---- stage xs -> LDS (coalesced), pull own row to regs ----
    {
        const float4* src = reinterpret_cast<const float4*>(xs_g + blockBase);
        for (int idx = tid; idx < K3_F4; idx += K3_ROWS) lds4[idx] = src[idx];
    }
    __syncthreads();
#pragma unroll
    for (int c = 0; c < D / 4; c++) {
        float4 t = myrow4[c];
        v0[c * 4] = t.x; v0[c * 4 + 1] = t.y; v0[c * 4 + 2] = t.z; v0[c * 4 + 3] = t.w;
    }
    __syncthreads();

    // ---- stage xl -> LDS, pull own row to regs, compute s0 ----
    {
        const float4* src = reinterpret_cast<const float4*>(xl_g + blockBase);
        for (int idx = tid; idx < K3_F4; idx += K3_ROWS) lds4[idx] = src[idx];
    }
    __syncthreads();
#pragma unroll
    for (int c = 0; c < D / 4; c++) {
        float4 t = myrow4[c];
        v1[c * 4] = t.x; v1[c * 4 + 1] = t.y; v1[c * 4 + 2] = t.z; v1[c * 4 + 3] = t.w;
    }
    float s0 = bilin(Msl, v0, myrow);  // (sub regs, left lds)
    __syncthreads();

    // ---- stage xr -> LDS, compute s1, s2 ----
    {
        const float4* src = reinterpret_cast<const float4*>(xr_g + blockBase);
        for (int idx = tid; idx < K3_F4; idx += K3_ROWS) lds4[idx] = src[idx];
    }
    __syncthreads();
    float s1 = bilin(Msr, v0, myrow);  // (sub regs, right lds)
    float s2 = bilin(Mlr, v1, myrow);  // (left regs, right lds)

    // ---- softmax + combine (in-place into own LDS row), coalesced store ----
    float m = fmaxf(s0, fmaxf(s1, s2));
    float e0 = __expf(s0 - m), e1 = __expf(s1 - m), e2 = __expf(s2 - m);
    float inv = 1.0f / (e0 + e1 + e2);
    float p0 = e0 * inv, p1 = e1 * inv, p2 = e2 * inv;  // left, right, sub

    float4* myrow4w = reinterpret_cast<float4*>(myrow);
#pragma unroll
    for (int c = 0; c < D / 4; c++) {
        float4 r4 = myrow4[c];  // right
        float4 o;
        o.x = p0 * v1[c * 4 + 0] + p1 * r4.x + p2 * v0[c * 4 + 0];
        o.y = p0 * v1[c * 4 + 1] + p1 * r4.y + p2 * v0[c * 4 + 1];
        o.z = p0 * v1[c * 4 + 2] + p1 * r4.z + p2 * v0[c * 4 + 2];
        o.w = p0 * v1[c * 4 + 3] + p1 * r4.w + p2 * v0[c * 4 + 3];
        myrow4w[c] = o;  // own row: no barrier needed
    }
    __syncthreads();
    {
        float4* dst = reinterpret_cast<float4*>(out + blockBase);
        for (int idx = tid; idx < K3_F4; idx += K3_ROWS) dst[idx] = lds4[idx];
    }
}

// ---------------------------------------------------------------------------
extern "C" void kernel_launch(void* const* d_in, const int* in_sizes, int n_in,
                              void* d_out, int out_size, void* d_ws, size_t ws_size,
                              hipStream_t stream) {
    const float* xs = (const float*)d_in[0];
    const float* xl = (const float*)d_in[1];
    const float* xr = (const float*)d_in[2];
    const float* Wsub = (const float*)d_in[3];
    const float* bsub = (const float*)d_in[4];
    const float* gsub = (const float*)d_in[5];
    const float* besub = (const float*)d_in[6];
    const float* Wleft = (const float*)d_in[7];
    const float* bleft = (const float*)d_in[8];
    const float* gleft = (const float*)d_in[9];
    const float* beleft = (const float*)d_in[10];
    const float* Wright = (const float*)d_in[11];
    const float* bright = (const float*)d_in[12];
    const float* gright = (const float*)d_in[13];
    const float* beright = (const float*)d_in[14];
    float* ws = (float*)d_ws;
    float* out = (float*)d_out;

    hipMemsetAsync(ws + S_OFF, 0, 3 * S_SIZE * sizeof(float), stream);

    k1_moments<<<dim3(256, 3), 256, 0, stream>>>(xs, xl, xr, ws);
    k2_T<<<(3 * DOUT * DA + 255) / 256, 256, 0, stream>>>(
        Wsub, bsub, Wleft, bleft, Wright, bright, ws);
    k2_scale<<<(3 * DOUT + 255) / 256, 256, 0, stream>>>(
        Wsub, bsub, gsub, besub, Wleft, bleft, gleft, beleft,
        Wright, bright, gright, beright, ws);
    k2_M<<<(3 * DA * DA + 255) / 256, 256, 0, stream>>>(ws);
    k3_main<<<N_ROWS / K3_ROWS, K3_ROWS, 0, stream>>>(xs, xl, xr, ws, out);
}